// Round 14
// baseline (86.885 us; speedup 1.0000x reference)
//
#include <hip/hip_runtime.h>
#include <hip/hip_bf16.h>

typedef __bf16 bf16x8 __attribute__((ext_vector_type(8)));
typedef float  f32x4  __attribute__((ext_vector_type(4)));

#define IN_F   4096
#define OUT_F  4096
#define RANK   32

__device__ __forceinline__ bf16x8 cvt8(float4 a, float4 b) {
    bf16x8 r;
    r[0] = (__bf16)a.x; r[1] = (__bf16)a.y; r[2] = (__bf16)a.z; r[3] = (__bf16)a.w;
    r[4] = (__bf16)b.x; r[5] = (__bf16)b.y; r[6] = (__bf16)b.z; r[7] = (__bf16)b.w;
    return r;
}

__device__ __forceinline__ void gl_lds16(const float* g, void* l) {
    __builtin_amdgcn_global_load_lds(
        (const __attribute__((address_space(1))) char*)g,
        (__attribute__((address_space(3))) char*)l, 16, 0, 0);
}

// ---------------- Kernel 1 (R13 exact): Hpart[ks] = (X @ V^T) * S ----------------
template <int KS>
__global__ __launch_bounds__(256, 2)
void lora_h(const float* __restrict__ X, const float* __restrict__ S,
            const float* __restrict__ V, float* __restrict__ Hpart)
{
    constexpr int F    = IN_F / KS;
    constexpr int NCHK = F / 64;

    __shared__ float4 XB[3][4][2][2][64];  // 48 KB
    __shared__ float4 VB[3][2][2][2][64];  // 24 KB

    const int tid  = threadIdx.x;
    const int wave = tid >> 6;
    const int lane = tid & 63;
    const int r    = lane & 15;
    const int kg   = lane >> 4;

    const int t0    = blockIdx.x * 64;
    const int fbase = blockIdx.y * F;

    const float s_lo = S[r];
    const float s_hi = S[16 + r];

    auto stage = [&](int c, int nb) {
        const int fc = fbase + ((c + blockIdx.x) & (NCHK - 1)) * 64;
        #pragma unroll
        for (int t = 0; t < 6; ++t) {
            const int inst = wave * 6 + t;
            if (inst < 16) {
                const int tt = inst >> 2, s = (inst >> 1) & 1, h2 = inst & 1;
                gl_lds16(X + (size_t)(t0 + tt * 16 + r) * IN_F
                           + fc + s * 32 + h2 * 16 + kg * 4,
                         (void*)&XB[nb][tt][s][h2][0]);
            } else {
                const int v = inst - 16;
                const int vr = v >> 2, s = (v >> 1) & 1, h2 = v & 1;
                gl_lds16(V + (size_t)(vr * 16 + r) * IN_F
                           + fc + s * 32 + h2 * 16 + kg * 4,
                         (void*)&VB[nb][vr][s][h2][0]);
            }
        }
    };

    const int h  = kg >> 1;
    const int qb = (kg & 1) * 2;

    f32x4 acc[2] = {};

    auto compute = [&](int cur) {
        #pragma unroll
        for (int s = 0; s < 2; ++s) {
            float4 x0 = *(const float4*)&XB[cur][wave][s][h][qb * 16 + r];
            float4 x1 = *(const float4*)&XB[cur][wave][s][h][(qb + 1) * 16 + r];
            bf16x8 xb = cvt8(x0, x1);
            #pragma unroll
            for (int rh = 0; rh < 2; ++rh) {
                float4 v0 = *(const float4*)&VB[cur][rh][s][h][qb * 16 + r];
                float4 v1 = *(const float4*)&VB[cur][rh][s][h][(qb + 1) * 16 + r];
                acc[rh] = __builtin_amdgcn_mfma_f32_16x16x32_bf16(
                              xb, cvt8(v0, v1), acc[rh], 0, 0, 0);
            }
        }
    };

    stage(0, 0);
    stage(1, 1);

    for (int c = 0; c < NCHK; ++c) {
        if (c + 2 < NCHK) {
            stage(c + 2, (c + 2) % 3);
            asm volatile("s_waitcnt vmcnt(12)" ::: "memory");
        } else if (c + 1 < NCHK) {
            asm volatile("s_waitcnt vmcnt(6)" ::: "memory");
        } else {
            asm volatile("s_waitcnt vmcnt(0)" ::: "memory");
        }
        __builtin_amdgcn_s_barrier();
        __builtin_amdgcn_sched_barrier(0);
        compute(c % 3);
        __builtin_amdgcn_s_barrier();
    }

    float* Hq = Hpart + ((size_t)blockIdx.y * 8192 + t0) * RANK;
    #pragma unroll
    for (int j = 0; j < 4; ++j) {
        const int tok = wave * 16 + kg * 4 + j;
        Hq[(size_t)tok * RANK + r]      = acc[0][j] * s_lo;
        Hq[(size_t)tok * RANK + 16 + r] = acc[1][j] * s_hi;
    }
}

// ---------------- Kernel 1.5: H = sum_k Hpart[k] ----------------
template <int NKS>
__global__ __launch_bounds__(256)
void lora_hred(const float* __restrict__ Hpart, float* __restrict__ H)
{
    const int idx = blockIdx.x * 256 + threadIdx.x;
    const float4* hp = reinterpret_cast<const float4*>(Hpart);
    float4 v = hp[idx];
    #pragma unroll
    for (int k = 1; k < NKS; ++k) {
        float4 p = hp[(size_t)k * 65536 + idx];
        v.x += p.x; v.y += p.y; v.z += p.z; v.w += p.w;
    }
    reinterpret_cast<float4*>(H)[idx] = v;
}

// ---------------- Kernel 2 (R13 exact): Out = H @ U^T ----------------
__global__ __launch_bounds__(256, 4)
void lora_out(const float* __restrict__ H, const float* __restrict__ U,
              float* __restrict__ Out)
{
    __shared__ float Hs[32][33];

    const int tid  = threadIdx.x;
    const int wave = tid >> 6;
    const int lane = tid & 63;
    const int r    = lane & 15;
    const int kg   = lane >> 4;

    const int tt = blockIdx.x >> 2;
    const int cq = blockIdx.x & 3;
    const int t0 = tt * 32;

    {
        float4 v = reinterpret_cast<const float4*>(H + (size_t)t0 * RANK)[tid];
        const int tok = tid >> 3;
        const int rr  = (tid & 7) * 4;
        Hs[tok][rr] = v.x; Hs[tok][rr + 1] = v.y;
        Hs[tok][rr + 2] = v.z; Hs[tok][rr + 3] = v.w;
    }
    __syncthreads();

    bf16x8 hb[2];
    #pragma unroll
    for (int a = 0; a < 2; ++a)
        #pragma unroll
        for (int j = 0; j < 8; ++j) hb[a][j] = (__bf16)Hs[a * 16 + r][kg * 8 + j];

    const int wc0 = cq * 1024 + wave * 256;

    #pragma unroll
    for (int g = 0; g < 4; ++g) {
        float4 u0[4], u1[4];
        #pragma unroll
        for (int b = 0; b < 4; ++b) {
            const float4* up = reinterpret_cast<const float4*>(
                U + (size_t)(wc0 + g * 64 + b * 16 + r) * RANK + kg * 8);
            u0[b] = up[0];
            u1[b] = up[1];
        }
        #pragma unroll
        for (int b = 0; b < 4; ++b) {
            bf16x8 ub = cvt8(u0[b], u1[b]);
            #pragma unroll
            for (int a = 0; a < 2; ++a) {
                f32x4 d = {0.f, 0.f, 0.f, 0.f};
                d = __builtin_amdgcn_mfma_f32_16x16x32_bf16(ub, hb[a], d, 0, 0, 0);
                *reinterpret_cast<float4*>(
                    Out + (size_t)(t0 + a * 16 + r) * OUT_F
                        + wc0 + g * 64 + b * 16 + kg * 4)
                    = *reinterpret_cast<float4*>(&d);
            }
        }
    }
}

// ---------------- PROBE: pure-read ceiling test ----------------
// Grid-stride float4 sum of all X (128 MB). 2048 blocks x 256 thr ->
// 8 blocks/CU, 32 waves/CU, 16 independent unrolled loads/thread.
// Per-wave sums stored deterministically into the (already consumed) H
// buffer. T_probe = dur(this round) - 67.0 measures the chip's sustained
// read throughput for this working set, independent of kernel structure.
__global__ __launch_bounds__(256)
void read_probe(const float* __restrict__ X, float* __restrict__ sink)
{
    const float4* x4 = reinterpret_cast<const float4*>(X);
    const int base = blockIdx.x * 256 + threadIdx.x;
    float acc = 0.f;
    #pragma unroll
    for (int i = 0; i < 16; ++i) {          // 16 x 524288 float4 = 8M float4 = 128 MB
        float4 v = x4[(size_t)i * 524288 + base];
        acc += v.x + v.y + v.z + v.w;
    }
    #pragma unroll
    for (int off = 32; off > 0; off >>= 1) acc += __shfl_down(acc, off);
    if ((threadIdx.x & 63) == 0)
        sink[blockIdx.x * 4 + (threadIdx.x >> 6)] = acc;
}

extern "C" void kernel_launch(void* const* d_in, const int* in_sizes, int n_in,
                              void* d_out, int out_size, void* d_ws, size_t ws_size,
                              hipStream_t stream) {
    const float* X = (const float*)d_in[0];
    const float* U = (const float*)d_in[1];
    const float* S = (const float*)d_in[2];
    const float* V = (const float*)d_in[3];
    float* Out = (float*)d_out;

    float* H     = (float*)d_ws;                 // 1 MB reduced H
    float* Hpart = (float*)d_ws + 262144;        // 4 MB partials (KS=4)

    if (ws_size >= (size_t)5 * 1024 * 1024) {
        lora_h<4><<<dim3(128, 4), 256, 0, stream>>>(X, S, V, Hpart);
        lora_hred<4><<<256, 256, 0, stream>>>(Hpart, H);
        lora_out<<<1024, 256, 0, stream>>>(H, U, Out);
        // probe LAST, writes into H (already consumed; deterministic values)
        read_probe<<<2048, 256, 0, stream>>>(X, H);
    } else {
        lora_h<1><<<dim3(128, 1), 256, 0, stream>>>(X, S, V, H);
        lora_out<<<1024, 256, 0, stream>>>(H, U, Out);
        read_probe<<<2048, 256, 0, stream>>>(X, H);
    }
}

// Round 15
// 69.115 us; speedup vs baseline: 1.2571x; 1.2571x over previous
//
#include <hip/hip_runtime.h>
#include <hip/hip_bf16.h>

typedef __bf16 bf16x8 __attribute__((ext_vector_type(8)));
typedef float  f32x4  __attribute__((ext_vector_type(4)));

#define IN_F   4096
#define OUT_F  4096
#define RANK   32

__device__ __forceinline__ bf16x8 cvt8(float4 a, float4 b) {
    bf16x8 r;
    r[0] = (__bf16)a.x; r[1] = (__bf16)a.y; r[2] = (__bf16)a.z; r[3] = (__bf16)a.w;
    r[4] = (__bf16)b.x; r[5] = (__bf16)b.y; r[6] = (__bf16)b.z; r[7] = (__bf16)b.w;
    return r;
}

// ---------------- Kernel 1 (probe-style): Hpart[slice] = X @ V^T ----------------
// grid (128, NSL/4), block 256 (4 waves). Wave = one slice of 4096/NSL feats
// for 64 tokens. NO LDS staging, NO barriers in the hot loop: plain float4
// fragment loads straight to VGPRs (12 independent 1KB loads per K-step,
// unroll 2 -> ~24 in flight), MFMA from registers — the structure the R14
// probe measured at 6.4 TB/s. 12 waves/CU via __launch_bounds__(256,3).
// Single end-of-kernel LDS reduce combines the block's 4 slices.
template <int NSL>
__global__ __launch_bounds__(256, 3)
void lora_h(const float* __restrict__ X, const float* __restrict__ S,
            const float* __restrict__ V, float* __restrict__ Hpart)
{
    constexpr int SL    = IN_F / NSL;   // feats per slice (wave)
    constexpr int STEPS = SL / 32;      // K-steps per wave

    __shared__ float Hp[4][64][33];     // per-wave partials, padded (33.8 KB)

    const int tid  = threadIdx.x;
    const int wave = tid >> 6;
    const int lane = tid & 63;
    const int r    = lane & 15;
    const int kg   = lane >> 4;

    const int t0 = blockIdx.x * 64;
    const int f0 = (blockIdx.y * 4 + wave) * SL;

    f32x4 acc[4][2] = {};               // [token-16-tile][rank-half]

    const float* xb0 = X + (size_t)(t0 + r) * IN_F + f0 + kg * 8;
    const float* vb0 = V + (size_t)r * IN_F + f0 + kg * 8;

    #pragma unroll 2
    for (int s = 0; s < STEPS; ++s) {
        const float* xc = xb0 + s * 32;
        const float* vc = vb0 + s * 32;
        // batch-issue all 12 independent loads for this K=32 step
        float4 v00 = *(const float4*)(vc);
        float4 v01 = *(const float4*)(vc + 4);
        float4 v10 = *(const float4*)(vc + (size_t)16 * IN_F);
        float4 v11 = *(const float4*)(vc + (size_t)16 * IN_F + 4);
        float4 x[4][2];
        #pragma unroll
        for (int tt = 0; tt < 4; ++tt) {
            x[tt][0] = *(const float4*)(xc + (size_t)tt * 16 * IN_F);
            x[tt][1] = *(const float4*)(xc + (size_t)tt * 16 * IN_F + 4);
        }
        bf16x8 vbf0 = cvt8(v00, v01);
        bf16x8 vbf1 = cvt8(v10, v11);
        #pragma unroll
        for (int tt = 0; tt < 4; ++tt) {
            bf16x8 xb = cvt8(x[tt][0], x[tt][1]);
            // A = X (m = token), B = V (n = rank-in-half)
            acc[tt][0] = __builtin_amdgcn_mfma_f32_16x16x32_bf16(xb, vbf0, acc[tt][0], 0, 0, 0);
            acc[tt][1] = __builtin_amdgcn_mfma_f32_16x16x32_bf16(xb, vbf1, acc[tt][1], 0, 0, 0);
        }
    }

    // D: token = tt*16 + kg*4 + j, rank = rh*16 + r
    #pragma unroll
    for (int tt = 0; tt < 4; ++tt)
        #pragma unroll
        for (int rh = 0; rh < 2; ++rh)
            #pragma unroll
            for (int j = 0; j < 4; ++j)
                Hp[wave][tt * 16 + kg * 4 + j][rh * 16 + r] = acc[tt][rh][j];
    __syncthreads();

    // reduce the block's 4 slices, apply S, write block partial (8 KB contiguous)
    float* dst = Hpart + (size_t)blockIdx.y * (8192 * RANK) + (size_t)t0 * RANK;
    for (int i = tid; i < 64 * RANK; i += 256) {
        const int tok = i >> 5, rk = i & 31;
        const float sum = Hp[0][tok][rk] + Hp[1][tok][rk]
                        + Hp[2][tok][rk] + Hp[3][tok][rk];
        dst[i] = sum * S[rk];           // SCALING == 1.0 folded
    }
}

// ---------------- Kernel 1.5: H = sum_k Hpart[k] ----------------
template <int NKS>
__global__ __launch_bounds__(256)
void lora_hred(const float* __restrict__ Hpart, float* __restrict__ H)
{
    const int idx = blockIdx.x * 256 + threadIdx.x;       // float4 idx, 65536 total
    const float4* hp = reinterpret_cast<const float4*>(Hpart);
    float4 v = hp[idx];
    #pragma unroll
    for (int k = 1; k < NKS; ++k) {
        float4 p = hp[(size_t)k * 65536 + idx];
        v.x += p.x; v.y += p.y; v.z += p.z; v.w += p.w;
    }
    reinterpret_cast<float4*>(H)[idx] = v;
}

// ---------------- Kernel 2 (R13 exact, proven ~9.5 µs): Out = H @ U^T ----------------
__global__ __launch_bounds__(256, 4)
void lora_out(const float* __restrict__ H, const float* __restrict__ U,
              float* __restrict__ Out)
{
    __shared__ float Hs[32][33];

    const int tid  = threadIdx.x;
    const int wave = tid >> 6;
    const int lane = tid & 63;
    const int r    = lane & 15;
    const int kg   = lane >> 4;

    const int tt = blockIdx.x >> 2;
    const int cq = blockIdx.x & 3;
    const int t0 = tt * 32;

    {
        float4 v = reinterpret_cast<const float4*>(H + (size_t)t0 * RANK)[tid];
        const int tok = tid >> 3;
        const int rr  = (tid & 7) * 4;
        Hs[tok][rr] = v.x; Hs[tok][rr + 1] = v.y;
        Hs[tok][rr + 2] = v.z; Hs[tok][rr + 3] = v.w;
    }
    __syncthreads();

    bf16x8 hb[2];
    #pragma unroll
    for (int a = 0; a < 2; ++a)
        #pragma unroll
        for (int j = 0; j < 8; ++j) hb[a][j] = (__bf16)Hs[a * 16 + r][kg * 8 + j];

    const int wc0 = cq * 1024 + wave * 256;

    #pragma unroll
    for (int g = 0; g < 4; ++g) {
        float4 u0[4], u1[4];
        #pragma unroll
        for (int b = 0; b < 4; ++b) {
            const float4* up = reinterpret_cast<const float4*>(
                U + (size_t)(wc0 + g * 64 + b * 16 + r) * RANK + kg * 8);
            u0[b] = up[0];
            u1[b] = up[1];
        }
        #pragma unroll
        for (int b = 0; b < 4; ++b) {
            bf16x8 ub = cvt8(u0[b], u1[b]);
            #pragma unroll
            for (int a = 0; a < 2; ++a) {
                f32x4 d = {0.f, 0.f, 0.f, 0.f};
                d = __builtin_amdgcn_mfma_f32_16x16x32_bf16(ub, hb[a], d, 0, 0, 0);
                *reinterpret_cast<float4*>(
                    Out + (size_t)(t0 + a * 16 + r) * OUT_F
                        + wc0 + g * 64 + b * 16 + kg * 4)
                    = *reinterpret_cast<float4*>(&d);
            }
        }
    }
}

extern "C" void kernel_launch(void* const* d_in, const int* in_sizes, int n_in,
                              void* d_out, int out_size, void* d_ws, size_t ws_size,
                              hipStream_t stream) {
    const float* X = (const float*)d_in[0];
    const float* U = (const float*)d_in[1];
    const float* S = (const float*)d_in[2];
    const float* V = (const float*)d_in[3];
    float* Out = (float*)d_out;

    float* H     = (float*)d_ws;                 // 1 MB reduced H
    float* Hpart = (float*)d_ws + 262144;        // up to 8 MB partials

    if (ws_size >= (size_t)10 * 1024 * 1024) {
        // 32 slices: 8 block-rows of 4 waves -> 8 partials, 4096 waves total
        lora_h<32><<<dim3(128, 8), 256, 0, stream>>>(X, S, V, Hpart);
        lora_hred<8><<<256, 256, 0, stream>>>(Hpart, H);
        lora_out<<<1024, 256, 0, stream>>>(H, U, Out);
    } else if (ws_size >= (size_t)6 * 1024 * 1024) {
        lora_h<16><<<dim3(128, 4), 256, 0, stream>>>(X, S, V, Hpart);
        lora_hred<4><<<256, 256, 0, stream>>>(Hpart, H);
        lora_out<<<1024, 256, 0, stream>>>(H, U, Out);
    } else {
        // single block-row covers all features -> writes final H directly
        lora_h<4><<<dim3(128, 1), 256, 0, stream>>>(X, S, V, H);
        lora_out<<<1024, 256, 0, stream>>>(H, U, Out);
    }
}

// Round 16
// 63.807 us; speedup vs baseline: 1.3617x; 1.0832x over previous
//
#include <hip/hip_runtime.h>
#include <hip/hip_bf16.h>

typedef __bf16 bf16x8 __attribute__((ext_vector_type(8)));
typedef float  f32x4  __attribute__((ext_vector_type(4)));

#define IN_F   4096
#define OUT_F  4096
#define RANK   32

__device__ __forceinline__ bf16x8 cvt8(float4 a, float4 b) {
    bf16x8 r;
    r[0] = (__bf16)a.x; r[1] = (__bf16)a.y; r[2] = (__bf16)a.z; r[3] = (__bf16)a.w;
    r[4] = (__bf16)b.x; r[5] = (__bf16)b.y; r[6] = (__bf16)b.z; r[7] = (__bf16)b.w;
    return r;
}

__device__ __forceinline__ void gl_lds16(const float* g, void* l) {
    __builtin_amdgcn_global_load_lds(
        (const __attribute__((address_space(1))) char*)g,
        (__attribute__((address_space(3))) char*)l, 16, 0, 0);
}

// ---------------- Kernel 1: Hpart[ks] = (X @ V^T) * S ----------------
// R13's exact pipeline (triple-buffer, stage-ahead, counted vmcnt, raw
// s_barrier) with ONE change: every gl_lds instruction is now a CONTIGUOUS
// 1 KB span (4 complete 64-feat rows, lane i -> base + i*16) instead of a
// 16-row scatter. The fragment layout transform moves to LDS: sources are
// XOR-pre-permuted within each row's 128 B half (same address set ->
// coalescing preserved), and fragment ds_reads apply the matching XOR
// ((r&7)<<2), giving <=2-way bank aliasing (free).
template <int KS>
__global__ __launch_bounds__(256, 2)
void lora_h(const float* __restrict__ X, const float* __restrict__ S,
            const float* __restrict__ V, float* __restrict__ Hpart)
{
    constexpr int F    = IN_F / KS;
    constexpr int NCHK = F / 64;        // 64-feat chunks

    __shared__ float XL[3][64 * 64];    // [buf][row*64+col] 48 KB (16 KB/buf)
    __shared__ float VL[3][32 * 64];    // [buf][row*64+col] 24 KB ( 8 KB/buf)

    const int tid  = threadIdx.x;
    const int wave = tid >> 6;
    const int lane = tid & 63;
    const int r    = lane & 15;
    const int kg   = lane >> 4;

    const int t0    = blockIdx.x * 64;
    const int fbase = blockIdx.y * F;

    const float s_lo = S[r];
    const float s_hi = S[16 + r];

    const int srow = lane >> 4;         // this lane's row within the 4-row span
    const int scol = (lane & 15) * 4;   // this lane's float col (0..60)

    // stage chunk c into buffer nb: 24 contiguous-1KB instructions, 6/wave
    auto stage = [&](int c, int nb) {
        const int fc = fbase + ((c + blockIdx.x) & (NCHK - 1)) * 64;
        #pragma unroll
        for (int t = 0; t < 6; ++t) {
            const int inst = wave * 6 + t;
            if (inst < 16) {            // X: instr i covers rows 4i..4i+3
                const int row = inst * 4 + srow;
                const int col = scol ^ ((row & 7) << 2);   // pre-swizzle
                gl_lds16(X + (size_t)(t0 + row) * IN_F + fc + col,
                         (void*)&XL[nb][inst * 256]);
            } else {                    // V: instr j covers rows 4j..4j+3
                const int j   = inst - 16;
                const int row = j * 4 + srow;
                const int col = scol ^ ((row & 7) << 2);
                gl_lds16(V + (size_t)row * IN_F + fc + col,
                         (void*)&VL[nb][j * 256]);
            }
        }
    };

    f32x4 acc[2] = {};                  // rank halves for this wave's 16 tokens

    auto compute = [&](int cur) {
        const int sw = (r & 7) << 2;    // read-side swizzle (matches source)
        #pragma unroll
        for (int s = 0; s < 2; ++s) {
            const int base = s * 32 + kg * 8;
            const int xrow = (wave * 16 + r) * 64;
            float4 x0 = *(const float4*)&XL[cur][xrow + ((base)     ^ sw)];
            float4 x1 = *(const float4*)&XL[cur][xrow + ((base + 4) ^ sw)];
            bf16x8 xb = cvt8(x0, x1);
            #pragma unroll
            for (int rh = 0; rh < 2; ++rh) {
                const int vrow = (rh * 16 + r) * 64;
                float4 v0 = *(const float4*)&VL[cur][vrow + ((base)     ^ sw)];
                float4 v1 = *(const float4*)&VL[cur][vrow + ((base + 4) ^ sw)];
                // A = X (m = token), B = V (n = rank-in-half)
                acc[rh] = __builtin_amdgcn_mfma_f32_16x16x32_bf16(
                              xb, cvt8(v0, v1), acc[rh], 0, 0, 0);
            }
        }
    };

    stage(0, 0);
    stage(1, 1);

    for (int c = 0; c < NCHK; ++c) {
        if (c + 2 < NCHK) {
            stage(c + 2, (c + 2) % 3);
            asm volatile("s_waitcnt vmcnt(12)" ::: "memory");
        } else if (c + 1 < NCHK) {
            asm volatile("s_waitcnt vmcnt(6)" ::: "memory");
        } else {
            asm volatile("s_waitcnt vmcnt(0)" ::: "memory");
        }
        __builtin_amdgcn_s_barrier();
        __builtin_amdgcn_sched_barrier(0);
        compute(c % 3);
        __builtin_amdgcn_s_barrier();
    }

    // D: token = wave*16 + kg*4 + j, rank = rh*16 + r. Direct global store.
    float* Hq = Hpart + ((size_t)blockIdx.y * 8192 + t0) * RANK;
    #pragma unroll
    for (int j = 0; j < 4; ++j) {
        const int tok = wave * 16 + kg * 4 + j;
        Hq[(size_t)tok * RANK + r]      = acc[0][j] * s_lo;
        Hq[(size_t)tok * RANK + 16 + r] = acc[1][j] * s_hi;
    }
}

// ---------------- Kernel 1.5: H = sum_k Hpart[k] ----------------
template <int NKS>
__global__ __launch_bounds__(256)
void lora_hred(const float* __restrict__ Hpart, float* __restrict__ H)
{
    const int idx = blockIdx.x * 256 + threadIdx.x;       // float4 idx, 65536
    const float4* hp = reinterpret_cast<const float4*>(Hpart);
    float4 v = hp[idx];
    #pragma unroll
    for (int k = 1; k < NKS; ++k) {
        float4 p = hp[(size_t)k * 65536 + idx];
        v.x += p.x; v.y += p.y; v.z += p.z; v.w += p.w;
    }
    reinterpret_cast<float4*>(H)[idx] = v;
}

// ---------------- Kernel 2 (R13 exact, proven ~9.5 µs): Out = H @ U^T ------------
__global__ __launch_bounds__(256, 4)
void lora_out(const float* __restrict__ H, const float* __restrict__ U,
              float* __restrict__ Out)
{
    __shared__ float Hs[32][33];

    const int tid  = threadIdx.x;
    const int wave = tid >> 6;
    const int lane = tid & 63;
    const int r    = lane & 15;
    const int kg   = lane >> 4;

    const int tt = blockIdx.x >> 2;
    const int cq = blockIdx.x & 3;
    const int t0 = tt * 32;

    {
        float4 v = reinterpret_cast<const float4*>(H + (size_t)t0 * RANK)[tid];
        const int tok = tid >> 3;
        const int rr  = (tid & 7) * 4;
        Hs[tok][rr] = v.x; Hs[tok][rr + 1] = v.y;
        Hs[tok][rr + 2] = v.z; Hs[tok][rr + 3] = v.w;
    }
    __syncthreads();

    bf16x8 hb[2];
    #pragma unroll
    for (int a = 0; a < 2; ++a)
        #pragma unroll
        for (int j = 0; j < 8; ++j) hb[a][j] = (__bf16)Hs[a * 16 + r][kg * 8 + j];

    const int wc0 = cq * 1024 + wave * 256;

    #pragma unroll
    for (int g = 0; g < 4; ++g) {
        float4 u0[4], u1[4];
        #pragma unroll
        for (int b = 0; b < 4; ++b) {
            const float4* up = reinterpret_cast<const float4*>(
                U + (size_t)(wc0 + g * 64 + b * 16 + r) * RANK + kg * 8);
            u0[b] = up[0];
            u1[b] = up[1];
        }
        #pragma unroll
        for (int b = 0; b < 4; ++b) {
            bf16x8 ub = cvt8(u0[b], u1[b]);
            #pragma unroll
            for (int a = 0; a < 2; ++a) {
                f32x4 d = {0.f, 0.f, 0.f, 0.f};
                d = __builtin_amdgcn_mfma_f32_16x16x32_bf16(ub, hb[a], d, 0, 0, 0);
                *reinterpret_cast<float4*>(
                    Out + (size_t)(t0 + a * 16 + r) * OUT_F
                        + wc0 + g * 64 + b * 16 + kg * 4)
                    = *reinterpret_cast<float4*>(&d);
            }
        }
    }
}

extern "C" void kernel_launch(void* const* d_in, const int* in_sizes, int n_in,
                              void* d_out, int out_size, void* d_ws, size_t ws_size,
                              hipStream_t stream) {
    const float* X = (const float*)d_in[0];
    const float* U = (const float*)d_in[1];
    const float* S = (const float*)d_in[2];
    const float* V = (const float*)d_in[3];
    float* Out = (float*)d_out;

    float* H     = (float*)d_ws;                 // 1 MB reduced H
    float* Hpart = (float*)d_ws + 262144;        // 4 MB partials (KS=4)

    if (ws_size >= (size_t)5 * 1024 * 1024) {
        lora_h<4><<<dim3(128, 4), 256, 0, stream>>>(X, S, V, Hpart);
        lora_hred<4><<<256, 256, 0, stream>>>(Hpart, H);
        lora_out<<<1024, 256, 0, stream>>>(H, U, Out);
    } else {
        lora_h<1><<<dim3(128, 1), 256, 0, stream>>>(X, S, V, H);
        lora_out<<<1024, 256, 0, stream>>>(H, U, Out);
    }
}

// Round 17
// 62.343 us; speedup vs baseline: 1.3937x; 1.0235x over previous
//
#include <hip/hip_runtime.h>
#include <hip/hip_bf16.h>

typedef __bf16 bf16x8 __attribute__((ext_vector_type(8)));
typedef float  f32x4  __attribute__((ext_vector_type(4)));

#define IN_F   4096
#define OUT_F  4096
#define RANK   32

__device__ __forceinline__ bf16x8 cvt8(float4 a, float4 b) {
    bf16x8 r;
    r[0] = (__bf16)a.x; r[1] = (__bf16)a.y; r[2] = (__bf16)a.z; r[3] = (__bf16)a.w;
    r[4] = (__bf16)b.x; r[5] = (__bf16)b.y; r[6] = (__bf16)b.z; r[7] = (__bf16)b.w;
    return r;
}

__device__ __forceinline__ void gl_lds16(const float* g, void* l) {
    __builtin_amdgcn_global_load_lds(
        (const __attribute__((address_space(1))) char*)g,
        (__attribute__((address_space(3))) char*)l, 16, 0, 0);
}

// ---------------- Kernel 1: Hpart[ks] = (X @ V^T) * S ----------------
// R16's exact addressing/pipeline, ONE change: 512-thread blocks (8 waves)
// -> 16 waves/CU at the same 2 blocks/CU (72 KB triple-buffered LDS).
// Isolates wave-level memory concurrency 8 -> 16 on the staged structure.
// Stage = 3 contiguous-1KB gl_lds per wave per chunk (uniform), counted
// vmcnt(6)/(3)/(0). Wave = (token-tile, rank-half): 2 MFMA/chunk, acc f32x4.
template <int KS>
__global__ __launch_bounds__(512, 4)
void lora_h(const float* __restrict__ X, const float* __restrict__ S,
            const float* __restrict__ V, float* __restrict__ Hpart)
{
    constexpr int F    = IN_F / KS;
    constexpr int NCHK = F / 64;        // 64-feat chunks

    __shared__ float XL[3][64 * 64];    // [buf][row*64+col] 48 KB
    __shared__ float VL[3][32 * 64];    // [buf][row*64+col] 24 KB

    const int tid  = threadIdx.x;
    const int wave = tid >> 6;          // 0..7
    const int lane = tid & 63;
    const int r    = lane & 15;
    const int kg   = lane >> 4;

    const int tt = wave & 3;            // token 16-tile
    const int rh = wave >> 2;           // rank half

    const int t0    = blockIdx.x * 64;
    const int fbase = blockIdx.y * F;

    const float sr = S[rh * 16 + r];

    const int srow = lane >> 4;         // lane's row within each 4-row span
    const int scol = (lane & 15) * 4;   // lane's float col (0..60)

    // stage chunk c into buffer nb: 24 contiguous-1KB instructions, 3/wave
    auto stage = [&](int c, int nb) {
        const int fc = fbase + ((c + blockIdx.x) & (NCHK - 1)) * 64;
        #pragma unroll
        for (int t = 0; t < 3; ++t) {
            const int inst = wave * 3 + t;
            if (inst < 16) {            // X: instr i covers rows 4i..4i+3
                const int row = inst * 4 + srow;
                const int col = scol ^ ((row & 7) << 2);   // pre-swizzle
                gl_lds16(X + (size_t)(t0 + row) * IN_F + fc + col,
                         (void*)&XL[nb][inst * 256]);
            } else {                    // V: instr j covers rows 4j..4j+3
                const int j   = inst - 16;
                const int row = j * 4 + srow;
                const int col = scol ^ ((row & 7) << 2);
                gl_lds16(V + (size_t)row * IN_F + fc + col,
                         (void*)&VL[nb][j * 256]);
            }
        }
    };

    f32x4 acc = {0.f, 0.f, 0.f, 0.f};   // this wave's (tt, rh) 16x16 tile

    auto compute = [&](int cur) {
        const int sw = (r & 7) << 2;    // read-side swizzle (matches source)
        const int xrow = (tt * 16 + r) * 64;
        const int vrow = (rh * 16 + r) * 64;
        #pragma unroll
        for (int s = 0; s < 2; ++s) {
            const int base = s * 32 + kg * 8;
            float4 x0 = *(const float4*)&XL[cur][xrow + ((base)     ^ sw)];
            float4 x1 = *(const float4*)&XL[cur][xrow + ((base + 4) ^ sw)];
            float4 v0 = *(const float4*)&VL[cur][vrow + ((base)     ^ sw)];
            float4 v1 = *(const float4*)&VL[cur][vrow + ((base + 4) ^ sw)];
            // A = X (m = token), B = V (n = rank-in-half)
            acc = __builtin_amdgcn_mfma_f32_16x16x32_bf16(
                      cvt8(x0, x1), cvt8(v0, v1), acc, 0, 0, 0);
        }
    };

    stage(0, 0);
    stage(1, 1);

    for (int c = 0; c < NCHK; ++c) {
        if (c + 2 < NCHK) {
            stage(c + 2, (c + 2) % 3);
            asm volatile("s_waitcnt vmcnt(6)" ::: "memory");  // chunk c landed; c+1,c+2 in flight
        } else if (c + 1 < NCHK) {
            asm volatile("s_waitcnt vmcnt(3)" ::: "memory");
        } else {
            asm volatile("s_waitcnt vmcnt(0)" ::: "memory");
        }
        __builtin_amdgcn_s_barrier();
        __builtin_amdgcn_sched_barrier(0);
        compute(c % 3);
        __builtin_amdgcn_s_barrier();   // readers done before buf re-staged
    }

    // D: token = tt*16 + kg*4 + j, rank = rh*16 + r. Direct global store.
    float* Hq = Hpart + ((size_t)blockIdx.y * 8192 + t0) * RANK;
    #pragma unroll
    for (int j = 0; j < 4; ++j) {
        const int tok = tt * 16 + kg * 4 + j;
        Hq[(size_t)tok * RANK + rh * 16 + r] = acc[j] * sr;
    }
}

// ---------------- Kernel 1.5: H = sum_k Hpart[k] ----------------
template <int NKS>
__global__ __launch_bounds__(256)
void lora_hred(const float* __restrict__ Hpart, float* __restrict__ H)
{
    const int idx = blockIdx.x * 256 + threadIdx.x;       // float4 idx, 65536
    const float4* hp = reinterpret_cast<const float4*>(Hpart);
    float4 v = hp[idx];
    #pragma unroll
    for (int k = 1; k < NKS; ++k) {
        float4 p = hp[(size_t)k * 65536 + idx];
        v.x += p.x; v.y += p.y; v.z += p.z; v.w += p.w;
    }
    reinterpret_cast<float4*>(H)[idx] = v;
}

// ---------------- Kernel 2 (proven ~9.5 µs): Out = H @ U^T ----------------
__global__ __launch_bounds__(256, 4)
void lora_out(const float* __restrict__ H, const float* __restrict__ U,
              float* __restrict__ Out)
{
    __shared__ float Hs[32][33];

    const int tid  = threadIdx.x;
    const int wave = tid >> 6;
    const int lane = tid & 63;
    const int r    = lane & 15;
    const int kg   = lane >> 4;

    const int tt = blockIdx.x >> 2;
    const int cq = blockIdx.x & 3;
    const int t0 = tt * 32;

    {
        float4 v = reinterpret_cast<const float4*>(H + (size_t)t0 * RANK)[tid];
        const int tok = tid >> 3;
        const int rr  = (tid & 7) * 4;
        Hs[tok][rr] = v.x; Hs[tok][rr + 1] = v.y;
        Hs[tok][rr + 2] = v.z; Hs[tok][rr + 3] = v.w;
    }
    __syncthreads();

    bf16x8 hb[2];
    #pragma unroll
    for (int a = 0; a < 2; ++a)
        #pragma unroll
        for (int j = 0; j < 8; ++j) hb[a][j] = (__bf16)Hs[a * 16 + r][kg * 8 + j];

    const int wc0 = cq * 1024 + wave * 256;

    #pragma unroll
    for (int g = 0; g < 4; ++g) {
        float4 u0[4], u1[4];
        #pragma unroll
        for (int b = 0; b < 4; ++b) {
            const float4* up = reinterpret_cast<const float4*>(
                U + (size_t)(wc0 + g * 64 + b * 16 + r) * RANK + kg * 8);
            u0[b] = up[0];
            u1[b] = up[1];
        }
        #pragma unroll
        for (int b = 0; b < 4; ++b) {
            bf16x8 ub = cvt8(u0[b], u1[b]);
            #pragma unroll
            for (int a = 0; a < 2; ++a) {
                f32x4 d = {0.f, 0.f, 0.f, 0.f};
                d = __builtin_amdgcn_mfma_f32_16x16x32_bf16(ub, hb[a], d, 0, 0, 0);
                *reinterpret_cast<float4*>(
                    Out + (size_t)(t0 + a * 16 + r) * OUT_F
                        + wc0 + g * 64 + b * 16 + kg * 4)
                    = *reinterpret_cast<float4*>(&d);
            }
        }
    }
}

extern "C" void kernel_launch(void* const* d_in, const int* in_sizes, int n_in,
                              void* d_out, int out_size, void* d_ws, size_t ws_size,
                              hipStream_t stream) {
    const float* X = (const float*)d_in[0];
    const float* U = (const float*)d_in[1];
    const float* S = (const float*)d_in[2];
    const float* V = (const float*)d_in[3];
    float* Out = (float*)d_out;

    float* H     = (float*)d_ws;                 // 1 MB reduced H
    float* Hpart = (float*)d_ws + 262144;        // 4 MB partials (KS=4)

    if (ws_size >= (size_t)5 * 1024 * 1024) {
        lora_h<4><<<dim3(128, 4), 512, 0, stream>>>(X, S, V, Hpart);
        lora_hred<4><<<256, 256, 0, stream>>>(Hpart, H);
        lora_out<<<1024, 256, 0, stream>>>(H, U, Out);
    } else {
        lora_h<1><<<dim3(128, 1), 512, 0, stream>>>(X, S, V, H);
        lora_out<<<1024, 256, 0, stream>>>(H, U, Out);
    }
}